// Round 1
// baseline (177.118 us; speedup 1.0000x reference)
//
#include <hip/hip_runtime.h>
#include <math.h>

#define THREADS 256
#define CHUNK   2048
#define NPTS    8192
#define BATCH   8

__global__ __launch_bounds__(THREADS, 2)
void chamfer_kernel(const float* __restrict__ pred,
                    const float* __restrict__ target,
                    float* __restrict__ out,
                    float inv_count)
{
    __shared__ float4 lds[CHUNK];

    // direction: y==0 -> query=pred, db=target ; y==1 -> swapped
    const float* q  = (blockIdx.y == 0) ? pred   : target;
    const float* db = (blockIdx.y == 0) ? target : pred;

    const int blocks_per_batch = NPTS / THREADS;           // 32
    const int b    = blockIdx.x / blocks_per_batch;
    const int nblk = blockIdx.x % blocks_per_batch;
    const int n    = nblk * THREADS + threadIdx.x;

    // load this thread's query point (3 consecutive floats)
    const float* qp = q + ((size_t)b * NPTS + n) * 3;
    const float px = qp[0], py = qp[1], pz = qp[2];
    const float npx = -2.0f * px, npy = -2.0f * py, npz = -2.0f * pz;
    const float P = px * px + py * py + pz * pz;

    const float* dbB = db + (size_t)b * NPTS * 3;

    float m0 = INFINITY, m1 = INFINITY, m2 = INFINITY, m3 = INFINITY;

    for (int c0 = 0; c0 < NPTS; c0 += CHUNK) {
        // ---- stage CHUNK db points into LDS as (x,y,z,|t|^2) ----
        #pragma unroll
        for (int k = 0; k < CHUNK / THREADS; ++k) {
            const int j = k * THREADS + threadIdx.x;
            const float* tp = dbB + (size_t)(c0 + j) * 3;
            const float tx = tp[0], ty = tp[1], tz = tp[2];
            lds[j] = make_float4(tx, ty, tz,
                                 tx * tx + ty * ty + tz * tz);
        }
        __syncthreads();

        // ---- min over the chunk: 3 FMA + 1 min per pair ----
        #pragma unroll 2
        for (int j = 0; j < CHUNK; j += 4) {
            const float4 T0 = lds[j + 0];
            const float4 T1 = lds[j + 1];
            const float4 T2 = lds[j + 2];
            const float4 T3 = lds[j + 3];
            const float e0 = fmaf(npx, T0.x, fmaf(npy, T0.y, fmaf(npz, T0.z, T0.w)));
            const float e1 = fmaf(npx, T1.x, fmaf(npy, T1.y, fmaf(npz, T1.z, T1.w)));
            const float e2 = fmaf(npx, T2.x, fmaf(npy, T2.y, fmaf(npz, T2.z, T2.w)));
            const float e3 = fmaf(npx, T3.x, fmaf(npy, T3.y, fmaf(npz, T3.z, T3.w)));
            m0 = fminf(m0, e0);
            m1 = fminf(m1, e1);
            m2 = fminf(m2, e2);
            m3 = fminf(m3, e3);
        }
        __syncthreads();
    }

    // per-thread min distance, clamped at 0 (clamp commutes with min)
    float m = fminf(fminf(m0, m1), fminf(m2, m3));
    m = fmaxf(P + m, 0.0f);

    // ---- block reduction: wave shuffle, then across the 4 waves ----
    float v = m;
    #pragma unroll
    for (int off = 32; off > 0; off >>= 1)
        v += __shfl_down(v, off, 64);

    __shared__ float wsum[THREADS / 64];
    const int lane = threadIdx.x & 63;
    const int wid  = threadIdx.x >> 6;
    if (lane == 0) wsum[wid] = v;
    __syncthreads();

    if (threadIdx.x == 0) {
        float s = wsum[0] + wsum[1] + wsum[2] + wsum[3];
        atomicAdd(out, s * inv_count);
    }
}

extern "C" void kernel_launch(void* const* d_in, const int* in_sizes, int n_in,
                              void* d_out, int out_size, void* d_ws, size_t ws_size,
                              hipStream_t stream) {
    const float* pred   = (const float*)d_in[0];
    const float* target = (const float*)d_in[1];
    float* out = (float*)d_out;

    // d_out is poisoned with 0xAA before every launch — zero it first
    hipMemsetAsync(out, 0, sizeof(float), stream);

    dim3 grid(BATCH * (NPTS / THREADS), 2);  // (256, 2): x = batch*row-block, y = direction
    chamfer_kernel<<<grid, THREADS, 0, stream>>>(
        pred, target, out, 1.0f / (float)(BATCH * NPTS));
}

// Round 2
// 147.055 us; speedup vs baseline: 1.2044x; 1.2044x over previous
//
#include <hip/hip_runtime.h>
#include <math.h>

#define THREADS 256
#define NPTS    8192
#define BATCH   8
#define DIRS    2
#define QPT     4                    // queries per thread (register tile)
#define QPB     (THREADS * QPT)      // 1024 queries per block
#define QBLK    (NPTS / QPB)         // 8 query-blocks
#define DBS     4                    // database splits
#define DBC     (NPTS / DBS)         // 2048 db points per block
#define WS_ENTRIES (DIRS * BATCH * NPTS)   // 131072
#define WS_BYTES   (WS_ENTRIES * 4)        // 512 KB

// ---------------- main kernel: partial min over a db chunk ----------------
__global__ __launch_bounds__(THREADS, 2)
void chamfer_min_kernel(const float* __restrict__ pred,
                        const float* __restrict__ target,
                        unsigned* __restrict__ ws)
{
    __shared__ float4 lds[DBC];   // 32 KB: (x, y, z, |t|^2)

    const int bx  = blockIdx.x;
    const int dbs = bx & (DBS - 1);
    const int qb  = (bx >> 2) & (QBLK - 1);
    const int b   = (bx >> 5) & (BATCH - 1);
    const int dir = bx >> 8;

    const float* q  = dir ? target : pred;
    const float* db = dir ? pred   : target;
    const float* dbB = db + ((size_t)b * NPTS + (size_t)dbs * DBC) * 3;

    // stage this block's db chunk into LDS (one-time, 24 KB of reads)
    for (int k = threadIdx.x; k < DBC; k += THREADS) {
        const float* tp = dbB + (size_t)k * 3;
        const float tx = tp[0], ty = tp[1], tz = tp[2];
        lds[k] = make_float4(tx, ty, tz, tx * tx + ty * ty + tz * tz);
    }

    // 4 query points in registers
    float nx[QPT], ny[QPT], nz[QPT], mn[QPT];
    const int q0 = qb * QPB + threadIdx.x;
    #pragma unroll
    for (int k = 0; k < QPT; ++k) {
        const float* qp = q + ((size_t)b * NPTS + q0 + k * THREADS) * 3;
        const float x = qp[0], y = qp[1], z = qp[2];
        nx[k] = -2.0f * x; ny[k] = -2.0f * y; nz[k] = -2.0f * z;
        mn[k] = INFINITY;
    }
    __syncthreads();

    // inner loop: 1 ds_read_b128 broadcast feeds 16 VALU ops (4 queries)
    #pragma unroll 4
    for (int j = 0; j < DBC; ++j) {
        const float4 T = lds[j];
        #pragma unroll
        for (int k = 0; k < QPT; ++k) {
            const float e = fmaf(nx[k], T.x,
                            fmaf(ny[k], T.y,
                            fmaf(nz[k], T.z, T.w)));
            mn[k] = fminf(mn[k], e);
        }
    }

    // combine partial mins across the DBS blocks: order-preserving uint key
    #pragma unroll
    for (int k = 0; k < QPT; ++k) {
        const unsigned u   = __float_as_uint(mn[k]);
        const unsigned key = (u >> 31) ? ~u : (u | 0x80000000u);
        atomicMin(&ws[((size_t)dir * BATCH + b) * NPTS + q0 + k * THREADS], key);
    }
}

// ---------------- epilogue: decode, add |p|^2, clamp, mean-reduce ----------------
__global__ __launch_bounds__(THREADS)
void chamfer_finish_kernel(const float* __restrict__ pred,
                           const float* __restrict__ target,
                           const unsigned* __restrict__ ws,
                           float* __restrict__ out,
                           float inv_count)
{
    const int idx0 = blockIdx.x * (THREADS * 4) + threadIdx.x;
    float s = 0.0f;
    #pragma unroll
    for (int k = 0; k < 4; ++k) {
        const int idx = idx0 + k * THREADS;
        const int dir = idx >> 16;          // 65536 entries per direction
        const int rem = idx & 0xFFFF;
        const int b   = rem >> 13;          // 8192 per batch
        const int qi  = rem & (NPTS - 1);
        const float* q  = dir ? target : pred;
        const float* qp = q + ((size_t)b * NPTS + qi) * 3;
        const float x = qp[0], y = qp[1], z = qp[2];
        const unsigned key = ws[idx];
        const unsigned u   = (key >> 31) ? (key ^ 0x80000000u) : ~key;
        const float e = __uint_as_float(u);
        s += fmaxf(x * x + y * y + z * z + e, 0.0f);
    }

    // block reduction
    float v = s;
    #pragma unroll
    for (int off = 32; off > 0; off >>= 1)
        v += __shfl_down(v, off, 64);

    __shared__ float wsum[THREADS / 64];
    const int lane = threadIdx.x & 63;
    const int wid  = threadIdx.x >> 6;
    if (lane == 0) wsum[wid] = v;
    __syncthreads();
    if (threadIdx.x == 0)
        atomicAdd(out, (wsum[0] + wsum[1] + wsum[2] + wsum[3]) * inv_count);
}

// ---------------- fallback (R1 single-kernel) if ws is too small ----------------
__global__ __launch_bounds__(THREADS, 2)
void chamfer_fallback_kernel(const float* __restrict__ pred,
                             const float* __restrict__ target,
                             float* __restrict__ out,
                             float inv_count)
{
    __shared__ float4 lds[2048];
    const float* q  = (blockIdx.y == 0) ? pred   : target;
    const float* db = (blockIdx.y == 0) ? target : pred;
    const int b = blockIdx.x / (NPTS / THREADS);
    const int n = (blockIdx.x % (NPTS / THREADS)) * THREADS + threadIdx.x;
    const float* qp = q + ((size_t)b * NPTS + n) * 3;
    const float px = qp[0], py = qp[1], pz = qp[2];
    const float npx = -2.0f * px, npy = -2.0f * py, npz = -2.0f * pz;
    const float P = px * px + py * py + pz * pz;
    const float* dbB = db + (size_t)b * NPTS * 3;
    float m0 = INFINITY;
    for (int c0 = 0; c0 < NPTS; c0 += 2048) {
        for (int k = 0; k < 2048 / THREADS; ++k) {
            const int j = k * THREADS + threadIdx.x;
            const float* tp = dbB + (size_t)(c0 + j) * 3;
            const float tx = tp[0], ty = tp[1], tz = tp[2];
            lds[j] = make_float4(tx, ty, tz, tx * tx + ty * ty + tz * tz);
        }
        __syncthreads();
        for (int j = 0; j < 2048; ++j) {
            const float4 T = lds[j];
            m0 = fminf(m0, fmaf(npx, T.x, fmaf(npy, T.y, fmaf(npz, T.z, T.w))));
        }
        __syncthreads();
    }
    float v = fmaxf(P + m0, 0.0f);
    #pragma unroll
    for (int off = 32; off > 0; off >>= 1)
        v += __shfl_down(v, off, 64);
    __shared__ float wsum[THREADS / 64];
    if ((threadIdx.x & 63) == 0) wsum[threadIdx.x >> 6] = v;
    __syncthreads();
    if (threadIdx.x == 0)
        atomicAdd(out, (wsum[0] + wsum[1] + wsum[2] + wsum[3]) * inv_count);
}

extern "C" void kernel_launch(void* const* d_in, const int* in_sizes, int n_in,
                              void* d_out, int out_size, void* d_ws, size_t ws_size,
                              hipStream_t stream) {
    const float* pred   = (const float*)d_in[0];
    const float* target = (const float*)d_in[1];
    float* out = (float*)d_out;

    hipMemsetAsync(out, 0, out_size * sizeof(float), stream);

    if (ws_size >= (size_t)WS_BYTES) {
        unsigned* ws = (unsigned*)d_ws;
        // init keys to 0xFFFFFFFF (= +max key, acts as +inf for atomicMin)
        hipMemsetAsync(ws, 0xFF, WS_BYTES, stream);
        dim3 grid(DIRS * BATCH * QBLK * DBS);   // 512 blocks
        chamfer_min_kernel<<<grid, THREADS, 0, stream>>>(pred, target, ws);
        chamfer_finish_kernel<<<WS_ENTRIES / (THREADS * 4), THREADS, 0, stream>>>(
            pred, target, ws, out, 1.0f / (float)(BATCH * NPTS));
    } else {
        dim3 grid(BATCH * (NPTS / THREADS), 2);
        chamfer_fallback_kernel<<<grid, THREADS, 0, stream>>>(
            pred, target, out, 1.0f / (float)(BATCH * NPTS));
    }
}

// Round 4
// 141.065 us; speedup vs baseline: 1.2556x; 1.0425x over previous
//
#include <hip/hip_runtime.h>
#include <math.h>

#define THREADS 256
#define NPTS    8192
#define BATCH   8
#define DIRS    2
#define QPT     8                    // queries per thread (register tile)
#define QPB     (THREADS * QPT)      // 2048 queries per block
#define QBLK    (NPTS / QPB)         // 4 query-blocks
#define DBS     16                   // database splits
#define DBC     (NPTS / DBS)         // 512 db points per block
#define WS_ENTRIES (DIRS * BATCH * NPTS)   // 131072
#define WS_BYTES   (WS_ENTRIES * 4)        // 512 KB

// ---------------- main kernel: partial min over a db chunk ----------------
__global__ __launch_bounds__(THREADS, 4)
void chamfer_min_kernel(const float* __restrict__ pred,
                        const float* __restrict__ target,
                        unsigned* __restrict__ ws)
{
    __shared__ float4 lds[DBC];   // 8 KB: (x, y, z, |t|^2)

    const int bx  = blockIdx.x;
    const int dbs = bx & (DBS - 1);
    const int qb  = (bx >> 4) & (QBLK - 1);
    const int b   = (bx >> 6) & (BATCH - 1);
    const int dir = bx >> 9;

    const float* q  = dir ? target : pred;
    const float* db = dir ? pred   : target;
    const float* dbB = db + ((size_t)b * NPTS + (size_t)dbs * DBC) * 3;

    // stage this block's db chunk into LDS (512 points, 2 iters)
    for (int k = threadIdx.x; k < DBC; k += THREADS) {
        const float* tp = dbB + (size_t)k * 3;
        const float tx = tp[0], ty = tp[1], tz = tp[2];
        lds[k] = make_float4(tx, ty, tz, tx * tx + ty * ty + tz * tz);
    }

    // 8 query points in registers
    float nx[QPT], ny[QPT], nz[QPT], mn[QPT];
    const int q0 = qb * QPB + threadIdx.x;
    #pragma unroll
    for (int k = 0; k < QPT; ++k) {
        const float* qp = q + ((size_t)b * NPTS + q0 + k * THREADS) * 3;
        const float x = qp[0], y = qp[1], z = qp[2];
        nx[k] = -2.0f * x; ny[k] = -2.0f * y; nz[k] = -2.0f * z;
        mn[k] = INFINITY;
    }
    __syncthreads();

    // inner loop: 2 ds_read_b128 broadcasts feed 8 queries x (6 FMA + 1 min3)
    #pragma unroll 4
    for (int j = 0; j < DBC; j += 2) {
        const float4 T0 = lds[j];
        const float4 T1 = lds[j + 1];
        #pragma unroll
        for (int k = 0; k < QPT; ++k) {
            const float e0 = fmaf(nx[k], T0.x,
                             fmaf(ny[k], T0.y,
                             fmaf(nz[k], T0.z, T0.w)));
            const float e1 = fmaf(nx[k], T1.x,
                             fmaf(ny[k], T1.y,
                             fmaf(nz[k], T1.z, T1.w)));
            mn[k] = fminf(mn[k], fminf(e0, e1));   // -> v_min3_f32
        }
    }

    // combine partial mins across the DBS blocks: order-preserving uint key
    #pragma unroll
    for (int k = 0; k < QPT; ++k) {
        const unsigned u   = __float_as_uint(mn[k]);
        const unsigned key = (u >> 31) ? ~u : (u | 0x80000000u);
        atomicMin(&ws[((size_t)dir * BATCH + b) * NPTS + q0 + k * THREADS], key);
    }
}

// ---------------- epilogue: decode, add |p|^2, clamp, mean-reduce ----------------
__global__ __launch_bounds__(THREADS)
void chamfer_finish_kernel(const float* __restrict__ pred,
                           const float* __restrict__ target,
                           const unsigned* __restrict__ ws,
                           float* __restrict__ out,
                           float inv_count)
{
    const int idx0 = blockIdx.x * (THREADS * 4) + threadIdx.x;
    float s = 0.0f;
    #pragma unroll
    for (int k = 0; k < 4; ++k) {
        const int idx = idx0 + k * THREADS;
        const int dir = idx >> 16;          // 65536 entries per direction
        const int rem = idx & 0xFFFF;
        const int b   = rem >> 13;          // 8192 per batch
        const int qi  = rem & (NPTS - 1);
        const float* q  = dir ? target : pred;
        const float* qp = q + ((size_t)b * NPTS + qi) * 3;
        const float x = qp[0], y = qp[1], z = qp[2];
        const unsigned key = ws[idx];
        const unsigned u   = (key >> 31) ? (key ^ 0x80000000u) : ~key;
        const float e = __uint_as_float(u);
        s += fmaxf(x * x + y * y + z * z + e, 0.0f);
    }

    // block reduction
    float v = s;
    #pragma unroll
    for (int off = 32; off > 0; off >>= 1)
        v += __shfl_down(v, off, 64);

    __shared__ float wsum[THREADS / 64];
    const int lane = threadIdx.x & 63;
    const int wid  = threadIdx.x >> 6;
    if (lane == 0) wsum[wid] = v;
    __syncthreads();
    if (threadIdx.x == 0)
        atomicAdd(out, (wsum[0] + wsum[1] + wsum[2] + wsum[3]) * inv_count);
}

// ---------------- fallback (R1 single-kernel) if ws is too small ----------------
__global__ __launch_bounds__(THREADS, 2)
void chamfer_fallback_kernel(const float* __restrict__ pred,
                             const float* __restrict__ target,
                             float* __restrict__ out,
                             float inv_count)
{
    __shared__ float4 lds[2048];
    const float* q  = (blockIdx.y == 0) ? pred   : target;
    const float* db = (blockIdx.y == 0) ? target : pred;
    const int b = blockIdx.x / (NPTS / THREADS);
    const int n = (blockIdx.x % (NPTS / THREADS)) * THREADS + threadIdx.x;
    const float* qp = q + ((size_t)b * NPTS + n) * 3;
    const float px = qp[0], py = qp[1], pz = qp[2];
    const float npx = -2.0f * px, npy = -2.0f * py, npz = -2.0f * pz;
    const float P = px * px + py * py + pz * pz;
    const float* dbB = db + (size_t)b * NPTS * 3;
    float m0 = INFINITY;
    for (int c0 = 0; c0 < NPTS; c0 += 2048) {
        for (int k = 0; k < 2048 / THREADS; ++k) {
            const int j = k * THREADS + threadIdx.x;
            const float* tp = dbB + (size_t)(c0 + j) * 3;
            const float tx = tp[0], ty = tp[1], tz = tp[2];
            lds[j] = make_float4(tx, ty, tz, tx * tx + ty * ty + tz * tz);
        }
        __syncthreads();
        for (int j = 0; j < 2048; ++j) {
            const float4 T = lds[j];
            m0 = fminf(m0, fmaf(npx, T.x, fmaf(npy, T.y, fmaf(npz, T.z, T.w))));
        }
        __syncthreads();
    }
    float v = fmaxf(P + m0, 0.0f);
    #pragma unroll
    for (int off = 32; off > 0; off >>= 1)
        v += __shfl_down(v, off, 64);
    __shared__ float wsum[THREADS / 64];
    if ((threadIdx.x & 63) == 0) wsum[threadIdx.x >> 6] = v;
    __syncthreads();
    if (threadIdx.x == 0)
        atomicAdd(out, (wsum[0] + wsum[1] + wsum[2] + wsum[3]) * inv_count);
}

extern "C" void kernel_launch(void* const* d_in, const int* in_sizes, int n_in,
                              void* d_out, int out_size, void* d_ws, size_t ws_size,
                              hipStream_t stream) {
    const float* pred   = (const float*)d_in[0];
    const float* target = (const float*)d_in[1];
    float* out = (float*)d_out;

    hipMemsetAsync(out, 0, out_size * sizeof(float), stream);

    if (ws_size >= (size_t)WS_BYTES) {
        unsigned* ws = (unsigned*)d_ws;
        // init keys to 0xFFFFFFFF (= +max key, acts as +inf for atomicMin)
        hipMemsetAsync(ws, 0xFF, WS_BYTES, stream);
        dim3 grid(DIRS * BATCH * QBLK * DBS);   // 1024 blocks -> 4 blocks/CU
        chamfer_min_kernel<<<grid, THREADS, 0, stream>>>(pred, target, ws);
        chamfer_finish_kernel<<<WS_ENTRIES / (THREADS * 4), THREADS, 0, stream>>>(
            pred, target, ws, out, 1.0f / (float)(BATCH * NPTS));
    } else {
        dim3 grid(BATCH * (NPTS / THREADS), 2);
        chamfer_fallback_kernel<<<grid, THREADS, 0, stream>>>(
            pred, target, out, 1.0f / (float)(BATCH * NPTS));
    }
}